// Round 19
// baseline (123.369 us; speedup 1.0000x reference)
//
#include <hip/hip_runtime.h>
#include <hip/hip_fp16.h>

#define NF 14
#define DIMOUT 16
#define BSH 9        // 512 nodes per bucket
#define NPBKT 512
#define NBKT 256     // bucket count (used: ceil(N/512) = 196)
#define C1 4096      // edges per block in bucket passes
#define QNODES 128   // nodes per quarter-bucket
#define SCAP4 7168   // LDS staging capacity (entries) per quarter-bucket
#define QSTRIDE 200  // quarter-major block stride (mod 8 == 0 -> bucket on 1 XCD)

// int64 edge buffer <=> odd 32-bit words (high halves) all zero (ids < 2^31)
__device__ __forceinline__ bool detect64(const int* e32) {
    bool is64 = true;
#pragma unroll
    for (int i = 1; i < 64; i += 2) is64 &= (e32[i] == 0);
    return is64;
}

// ---- per-block bucket histogram (transposed write); 16B paired loads ----
__global__ __launch_bounds__(256) void k_lhist(const void* __restrict__ edges,
                                               int* __restrict__ lhistT,
                                               int* __restrict__ done, int E, int NBLK) {
    __shared__ int h[NBKT];
    const int t = threadIdx.x;
    if (blockIdx.x == 0 && t == 0) *done = 0;  // reset cscan finalize ticket
    h[t] = 0;
    __syncthreads();
    const int* e32 = (const int*)edges;
    const long long* e64 = (const long long*)edges;
    const bool is64 = detect64(e32);
    const int base = blockIdx.x * C1;
    const int cnt = min(C1, E - base);  // always even (E, C1 even)
    if (is64) {
        const longlong2* p2 = (const longlong2*)(e64 + (size_t)E + base);
        for (int j = 2 * t; j < cnt; j += 512) {
            longlong2 v = p2[j >> 1];
            atomicAdd(&h[((int)v.x) >> BSH], 1);
            atomicAdd(&h[((int)v.y) >> BSH], 1);
        }
    } else {
        const int2* p2 = (const int2*)(e32 + (size_t)E + base);
        for (int j = 2 * t; j < cnt; j += 512) {
            int2 v = p2[j >> 1];
            atomicAdd(&h[v.x >> BSH], 1);
            atomicAdd(&h[v.y >> BSH], 1);
        }
    }
    __syncthreads();
    lhistT[(size_t)t * NBLK + blockIdx.x] = h[t];
}

// ---- per-bucket scan over blocks; LAST block also does the bucket-total
// scan (was k_gscan), zeroes the hbuild cursor and the sentinel u rows ----
__global__ __launch_bounds__(256) void k_cscan(const int* __restrict__ lhistT,
                                               int* __restrict__ lbase,
                                               int* __restrict__ btot,
                                               int* __restrict__ gregion,
                                               int* __restrict__ cursor,
                                               int* __restrict__ done,
                                               __half2* __restrict__ u0,
                                               __half2* __restrict__ u1,
                                               int NBLK, int N) {
    const int b = blockIdx.x;
    const int t = threadIdx.x;
    const int IPT = (NBLK + 255) / 256;
    int v[8];
    int s = 0;
    for (int k = 0; k < IPT; ++k) {
        int j = t * IPT + k;
        int x = (j < NBLK) ? lhistT[(size_t)b * NBLK + j] : 0;
        v[k] = x;
        s += x;
    }
    __shared__ int sm[256];
    __shared__ int ticket;
    sm[t] = s;
    __syncthreads();
    for (int d = 1; d < 256; d <<= 1) {
        int u = (t >= d) ? sm[t - d] : 0;
        __syncthreads();
        sm[t] += u;
        __syncthreads();
    }
    int run = sm[t] - s;
    for (int k = 0; k < IPT; ++k) {
        int j = t * IPT + k;
        if (j < NBLK) {
            lbase[(size_t)b * NBLK + j] = run;
            run += v[k];
        }
    }
    if (t == 255) btot[b] = sm[255];
    __syncthreads();
    if (t == 0) {
        __threadfence();
        ticket = atomicAdd(done, 1);
    }
    __syncthreads();
    if (ticket == NBKT - 1) {  // last-finishing block finalizes (deterministic result)
        __threadfence();
        int bv = btot[t];
        sm[t] = bv;
        __syncthreads();
        for (int d = 1; d < NBKT; d <<= 1) {
            int u = (t >= d) ? sm[t - d] : 0;
            __syncthreads();
            sm[t] += u;
            __syncthreads();
        }
        gregion[t] = sm[t] - bv;
        if (t == NBKT - 1) gregion[NBKT] = sm[t];
        if (t == 0) cursor[0] = 0;
        if (t < 8) {  // zero sentinel rows (src == N)
            u0[(size_t)N * 8 + t] = __floats2half2_rn(0.f, 0.f);
            u1[(size_t)N * 8 + t] = __floats2half2_rn(0.f, 0.f);
        }
    }
}

// ---- bucket scatter: block-local LDS counting sort, runs at exact bases ----
// packed entry: (dst & 511) << 17 | src ; 16B paired edge loads
__global__ __launch_bounds__(256) void k_scatter(const void* __restrict__ edges,
                                                 const int* __restrict__ gregion,
                                                 const int* __restrict__ lbase,
                                                 unsigned int* __restrict__ pairs,
                                                 int E, int NBLK) {
    __shared__ unsigned int raw[C1];
    __shared__ unsigned int srt[C1];
    __shared__ unsigned short bkt[C1];
    __shared__ unsigned char sbk[C1];
    __shared__ int hist[NBKT], scn[NBKT], gb[NBKT], cur[NBKT];
    const int* e32 = (const int*)edges;
    const long long* e64 = (const long long*)edges;
    const bool is64 = detect64(e32);
    const int t = threadIdx.x;
    const int base = blockIdx.x * C1;
    const int cnt = min(C1, E - base);  // always even
    hist[t] = 0;
    cur[t] = 0;
    __syncthreads();
    for (int j = 2 * t; j < cnt; j += 512) {
        int s0, s1, d0, d1;
        if (is64) {
            longlong2 vs = *(const longlong2*)(e64 + (size_t)base + j);
            longlong2 vd = *(const longlong2*)(e64 + (size_t)E + base + j);
            s0 = (int)vs.x;
            s1 = (int)vs.y;
            d0 = (int)vd.x;
            d1 = (int)vd.y;
        } else {
            int2 vs = *(const int2*)(e32 + (size_t)base + j);
            int2 vd = *(const int2*)(e32 + (size_t)E + base + j);
            s0 = vs.x;
            s1 = vs.y;
            d0 = vd.x;
            d1 = vd.y;
        }
        int b0 = d0 >> BSH, b1 = d1 >> BSH;
        raw[j] = (unsigned int)s0 | ((unsigned int)(d0 & (NPBKT - 1)) << 17);
        raw[j + 1] = (unsigned int)s1 | ((unsigned int)(d1 & (NPBKT - 1)) << 17);
        bkt[j] = (unsigned short)b0;
        bkt[j + 1] = (unsigned short)b1;
        atomicAdd(&hist[b0], 1);
        atomicAdd(&hist[b1], 1);
    }
    __syncthreads();
    int v = hist[t];
    scn[t] = v;
    __syncthreads();
    for (int d = 1; d < NBKT; d <<= 1) {
        int u = (t >= d) ? scn[t - d] : 0;
        __syncthreads();
        scn[t] += u;
        __syncthreads();
    }
    int ex = scn[t] - v;
    gb[t] = gregion[t] + lbase[(size_t)t * NBLK + blockIdx.x];
    __syncthreads();
    scn[t] = ex;
    __syncthreads();
    for (int j = t; j < cnt; j += 256) {
        int b = bkt[j];
        int r = atomicAdd(&cur[b], 1);
        int pos = scn[b] + r;
        srt[pos] = raw[j];
        sbk[pos] = (unsigned char)b;
    }
    __syncthreads();
    for (int j = t; j < cnt; j += 256) {
        int b = sbk[j];
        pairs[gb[b] + (j - scn[b])] = srt[j];
    }
}

// ---- fused quarter-bucket build: count -> reserve -> stage -> burst -> prep ----
// One block per quarter-bucket (128 nodes); stride-200 quarter-major mapping
// puts all 4 quarters of a bucket on one XCD (region fetched once). Counts
// degrees in LDS, reserves its srcs segment via one global atomicAdd, writes
// dinv/off2, stages self-loop + edges + sentinel pads, burst-writes, then
// computes u0[n] = fp16(dinv * (x[n] @ W^T)) (4 threads/node).
__global__ __launch_bounds__(512) void k_hbuild(const unsigned int* __restrict__ pairs,
                                                const int* __restrict__ gregion,
                                                int* __restrict__ cursor,
                                                const float* __restrict__ x,
                                                const float* __restrict__ Wg,
                                                float* __restrict__ dinv,
                                                int2* __restrict__ off2,
                                                int* __restrict__ srcs,
                                                __half2* __restrict__ u0,
                                                int N, int NUSED) {
    const int b = blockIdx.x % QSTRIDE;  // bucket
    const int q = blockIdx.x / QSTRIDE;  // quarter 0..3
    if (b >= NUSED) return;
    const int e0 = gregion[b], e1 = gregion[b + 1];
    __shared__ int cnt[QNODES], sm[QNODES], cur[QNODES];
    __shared__ float Wl[DIMOUT * NF];
    __shared__ unsigned staged[SCAP4];
    __shared__ int gb_sh;
    const int t = threadIdx.x;
    if (t < QNODES) cnt[t] = 0;
    if (t >= QNODES && t < QNODES + DIMOUT * NF) Wl[t - QNODES] = Wg[t - QNODES];
    __syncthreads();
    for (int e = e0 + t; e < e1; e += 512) {
        int dl = (int)(pairs[e] >> 17);
        if ((dl >> 7) == q) atomicAdd(&cnt[dl & (QNODES - 1)], 1);
    }
    __syncthreads();
    const int nbase = (b << BSH) + q * QNODES;
    int c = 0, p = 0;
    if (t < QNODES) {
        c = cnt[t];
        if (nbase + t < N) p = (c + 8) & ~7;  // self-loop + pad to 8
        sm[t] = p;
    }
    __syncthreads();
    for (int d = 1; d < QNODES; d <<= 1) {
        int u = (t >= d && t < QNODES) ? sm[t - d] : 0;
        __syncthreads();
        if (t < QNODES) sm[t] += u;
        __syncthreads();
    }
    const int span = sm[QNODES - 1];
    if (t == 0) gb_sh = atomicAdd(cursor, span);
    __syncthreads();
    const int gb = gb_sh;
    const bool fits = (span <= SCAP4);
    if (t < QNODES) {
        int n = nbase + t;
        if (n < N) {
            int loff = sm[t] - p;
            dinv[n] = rsqrtf((float)(c + 1));
            off2[n] = make_int2(gb + loff, gb + loff + p);
            if (fits) {
                cur[t] = loff + 1;
                staged[loff] = (unsigned)n;  // self loop at slot 0
                for (int k = c + 1; k < p; ++k) staged[loff + k] = (unsigned)N;
            } else {  // fallback: direct global writes
                cur[t] = gb + loff + 1;
                srcs[gb + loff] = n;
                for (int k = c + 1; k < p; ++k) srcs[gb + loff + k] = N;
            }
        } else {
            cur[t] = 0;
        }
    }
    __syncthreads();
    if (fits) {
        for (int e = e0 + t; e < e1; e += 512) {  // L2-hot re-read
            unsigned pr = pairs[e];
            int dl = (int)(pr >> 17);
            if ((dl >> 7) == q) {
                int r = atomicAdd(&cur[dl & (QNODES - 1)], 1);  // LDS only
                staged[r] = pr & 0x1FFFFu;
            }
        }
        __syncthreads();
        for (int i = t; i < span; i += 512) srcs[gb + i] = (int)staged[i];
    } else {
        for (int e = e0 + t; e < e1; e += 512) {
            unsigned pr = pairs[e];
            int dl = (int)(pr >> 17);
            if ((dl >> 7) == q) {
                int r = atomicAdd(&cur[dl & (QNODES - 1)], 1);
                srcs[r] = (int)(pr & 0x1FFFFu);
            }
        }
    }
    // ---- prep tail: 4 threads per node, 2 half2 outputs each.
    // Reads only cnt[] (stable since count phase) + global x/W — no sync needed.
    const int l4 = t >> 2;
    const int n4 = nbase + l4;
    if (n4 < N) {
        const int qb = (t & 3) * 2;
        float dn = rsqrtf((float)(cnt[l4] + 1));
        float xr[NF];
        const float2* xr2 = (const float2*)(x + (size_t)n4 * NF);
#pragma unroll
        for (int k = 0; k < 7; ++k) {
            float2 v = xr2[k];
            xr[2 * k] = v.x;
            xr[2 * k + 1] = v.y;
        }
#pragma unroll
        for (int qi = 0; qi < 2; ++qi) {
            const int qq = qb + qi;
            float r0 = 0.f, r1 = 0.f;
#pragma unroll
            for (int f = 0; f < NF; ++f) {
                r0 += xr[f] * Wl[(2 * qq) * NF + f];
                r1 += xr[f] * Wl[(2 * qq + 1) * NF + f];
            }
            u0[(size_t)n4 * 8 + qq] = __floats2half2_rn(dn * r0, dn * r1);
        }
    }
}

// ---- hop: grid-stride, 2 nodes per wave (half-wave each), 8-way
// edge-parallel, 8B lanes, pad-8 lists. Reduce over ep = 3 shfl rounds. ----
template <int FINAL>
__global__ __launch_bounds__(256) void k_hop(const uint2* __restrict__ u8,
                                             const int* __restrict__ srcs,
                                             const int2* __restrict__ off2,
                                             const float* __restrict__ dinv,
                                             const float* __restrict__ bias,
                                             uint2* __restrict__ outh,
                                             float* __restrict__ outf, int N) {
    const int lane = threadIdx.x & 63;
    const int fp = lane & 3;          // 8B quarter of 32B row
    const int ep = (lane >> 2) & 7;   // 8 edge subgroups per half-wave
    const int half = lane >> 5;       // which node this half-wave owns
    const int wid = threadIdx.x >> 6;
    float4 breg = make_float4(0.f, 0.f, 0.f, 0.f);
    if (FINAL) breg = *(const float4*)(bias + 4 * fp);
    const int stride = gridDim.x * 8;  // 4 waves x 2 nodes per block
    for (int n0 = blockIdx.x * 8 + wid * 2; n0 < N; n0 += stride) {
        const int n = n0 + half;
        const bool act = (n < N);
        int2 oo = act ? off2[n] : make_int2(0, 0);
        float ax = 0.f, ay = 0.f, az = 0.f, aw = 0.f;
        int e = oo.x + ep;
        for (; e + 8 < oo.y; e += 16) {  // 2-deep: 16 slots per half-wave iter
            int s0 = srcs[e];
            int s1 = srcs[e + 8];
            uint2 q0 = u8[(size_t)s0 * 4 + fp];
            uint2 q1 = u8[(size_t)s1 * 4 + fp];
            float2 a0 = __half22float2(*(__half2*)&q0.x);
            float2 b0 = __half22float2(*(__half2*)&q0.y);
            float2 a1 = __half22float2(*(__half2*)&q1.x);
            float2 b1 = __half22float2(*(__half2*)&q1.y);
            ax += a0.x + a1.x;
            ay += a0.y + a1.y;
            az += b0.x + b1.x;
            aw += b0.y + b1.y;
        }
        if (e < oo.y) {  // at most one leftover 8-chunk
            int s0 = srcs[e];
            uint2 q0 = u8[(size_t)s0 * 4 + fp];
            float2 a0 = __half22float2(*(__half2*)&q0.x);
            float2 b0 = __half22float2(*(__half2*)&q0.y);
            ax += a0.x;
            ay += a0.y;
            az += b0.x;
            aw += b0.y;
        }
#pragma unroll
        for (int d = 4; d <= 16; d <<= 1) {  // reduce over ep, stays in-half
            ax += __shfl_xor(ax, d);
            ay += __shfl_xor(ay, d);
            az += __shfl_xor(az, d);
            aw += __shfl_xor(aw, d);
        }
        if (ep == 0 && act) {
            float dn = dinv[n];
            if (!FINAL) {
                float s = dn * dn;
                __half2 h0 = __floats2half2_rn(s * ax, s * ay);
                __half2 h1 = __floats2half2_rn(s * az, s * aw);
                uint2 q;
                q.x = *(unsigned*)&h0;
                q.y = *(unsigned*)&h1;
                outh[(size_t)n * 4 + fp] = q;
            } else {
                float4 o;
                o.x = dn * ax + breg.x;
                o.y = dn * ay + breg.y;
                o.z = dn * az + breg.z;
                o.w = dn * aw + breg.w;
                *(float4*)(outf + (size_t)n * DIMOUT + 4 * fp) = o;
            }
        }
    }
}

extern "C" void kernel_launch(void* const* d_in, const int* in_sizes, int n_in,
                              void* d_out, int out_size, void* d_ws, size_t ws_size,
                              hipStream_t stream) {
    const float* x = (const float*)d_in[0];
    const void* edges = d_in[1];
    const float* W = (const float*)d_in[2];
    const float* b = (const float*)d_in[3];
    float* out = (float*)d_out;

    const int N = in_sizes[0] / NF;  // 100000
    const int E = in_sizes[1] / 2;   // 3200000
    const int NBLK = (E + C1 - 1) / C1;
    const int NUSED = (N + NPBKT - 1) >> BSH;

    char* ws = (char*)d_ws;
    size_t o = 0;
    auto alloc = [&](size_t bytes) -> void* {
        o = (o + 255) & ~(size_t)255;
        void* p = ws + o;
        o += bytes;
        return p;
    };
    int* cursor = (int*)alloc(16);
    int* done = (int*)alloc(16);
    int* lhistT = (int*)alloc((size_t)NBKT * NBLK * sizeof(int));
    int* lbase = (int*)alloc((size_t)NBKT * NBLK * sizeof(int));
    int* btot = (int*)alloc((size_t)NBKT * sizeof(int));
    int* gregion = (int*)alloc(((size_t)NBKT + 1) * sizeof(int));
    unsigned int* pairs = (unsigned int*)alloc((size_t)E * sizeof(unsigned int));
    int* srcs = (int*)alloc(((size_t)E + (size_t)8 * N + 256) * sizeof(int));
    int2* off2 = (int2*)alloc((size_t)N * sizeof(int2));
    float* dinv = (float*)alloc((size_t)N * sizeof(float));
    __half* u0 = (__half*)alloc((size_t)(N + 1) * 16 * sizeof(__half));
    __half* u1 = (__half*)alloc((size_t)(N + 1) * 16 * sizeof(__half));
    (void)ws_size;
    (void)n_in;
    (void)out_size;

    k_lhist<<<NBLK, 256, 0, stream>>>(edges, lhistT, done, E, NBLK);
    k_cscan<<<NBKT, 256, 0, stream>>>(lhistT, lbase, btot, gregion, cursor, done,
                                      (__half2*)u0, (__half2*)u1, NBLK, N);
    k_scatter<<<NBLK, 256, 0, stream>>>(edges, gregion, lbase, pairs, E, NBLK);
    k_hbuild<<<4 * QSTRIDE, 512, 0, stream>>>(pairs, gregion, cursor, x, W, dinv,
                                              off2, srcs, (__half2*)u0, N, NUSED);

    k_hop<0><<<2048, 256, 0, stream>>>((const uint2*)u0, srcs, off2, dinv, nullptr,
                                       (uint2*)u1, nullptr, N);
    k_hop<1><<<2048, 256, 0, stream>>>((const uint2*)u1, srcs, off2, dinv, b,
                                       nullptr, out, N);
}

// Round 20
// 120.350 us; speedup vs baseline: 1.0251x; 1.0251x over previous
//
#include <hip/hip_runtime.h>
#include <hip/hip_fp16.h>

#define NF 14
#define DIMOUT 16
#define BSH 9        // 512 nodes per bucket
#define NPBKT 512
#define NBKT 256     // bucket count (used: ceil(N/512) = 196)
#define C1 4096      // edges per block in bucket passes
#define HNODES 256   // nodes per half-bucket
#define SCAP 14336   // LDS staging capacity (entries) per half-bucket

// int64 edge buffer <=> odd 32-bit words (high halves) all zero (ids < 2^31)
__device__ __forceinline__ bool detect64(const int* e32) {
    bool is64 = true;
#pragma unroll
    for (int i = 1; i < 64; i += 2) is64 &= (e32[i] == 0);
    return is64;
}

// ---- per-block bucket histogram (transposed write); 16B paired loads ----
__global__ __launch_bounds__(256) void k_lhist(const void* __restrict__ edges,
                                               int* __restrict__ lhistT,
                                               int* __restrict__ done, int E, int NBLK) {
    __shared__ int h[NBKT];
    const int t = threadIdx.x;
    if (blockIdx.x == 0 && t == 0) *done = 0;  // reset cscan finalize ticket
    h[t] = 0;
    __syncthreads();
    const int* e32 = (const int*)edges;
    const long long* e64 = (const long long*)edges;
    const bool is64 = detect64(e32);
    const int base = blockIdx.x * C1;
    const int cnt = min(C1, E - base);  // always even (E, C1 even)
    if (is64) {
        const longlong2* p2 = (const longlong2*)(e64 + (size_t)E + base);
        for (int j = 2 * t; j < cnt; j += 512) {
            longlong2 v = p2[j >> 1];
            atomicAdd(&h[((int)v.x) >> BSH], 1);
            atomicAdd(&h[((int)v.y) >> BSH], 1);
        }
    } else {
        const int2* p2 = (const int2*)(e32 + (size_t)E + base);
        for (int j = 2 * t; j < cnt; j += 512) {
            int2 v = p2[j >> 1];
            atomicAdd(&h[v.x >> BSH], 1);
            atomicAdd(&h[v.y >> BSH], 1);
        }
    }
    __syncthreads();
    lhistT[(size_t)t * NBLK + blockIdx.x] = h[t];
}

// ---- per-bucket scan over blocks; LAST block also scans bucket totals
// (was k_gscan), zeroes the hbuild cursor and the sentinel u rows ----
__global__ __launch_bounds__(256) void k_cscan(const int* __restrict__ lhistT,
                                               int* __restrict__ lbase,
                                               int* __restrict__ btot,
                                               int* __restrict__ gregion,
                                               int* __restrict__ cursor,
                                               int* __restrict__ done,
                                               __half2* __restrict__ u0,
                                               __half2* __restrict__ u1,
                                               int NBLK, int N) {
    const int b = blockIdx.x;
    const int t = threadIdx.x;
    const int IPT = (NBLK + 255) / 256;
    int v[8];
    int s = 0;
    for (int k = 0; k < IPT; ++k) {
        int j = t * IPT + k;
        int x = (j < NBLK) ? lhistT[(size_t)b * NBLK + j] : 0;
        v[k] = x;
        s += x;
    }
    __shared__ int sm[256];
    __shared__ int ticket;
    sm[t] = s;
    __syncthreads();
    for (int d = 1; d < 256; d <<= 1) {
        int u = (t >= d) ? sm[t - d] : 0;
        __syncthreads();
        sm[t] += u;
        __syncthreads();
    }
    int run = sm[t] - s;
    for (int k = 0; k < IPT; ++k) {
        int j = t * IPT + k;
        if (j < NBLK) {
            lbase[(size_t)b * NBLK + j] = run;
            run += v[k];
        }
    }
    if (t == 255) btot[b] = sm[255];
    __syncthreads();
    if (t == 0) {
        __threadfence();
        ticket = atomicAdd(done, 1);
    }
    __syncthreads();
    if (ticket == NBKT - 1) {  // last-finishing block finalizes (deterministic)
        __threadfence();
        int bv = btot[t];
        sm[t] = bv;
        __syncthreads();
        for (int d = 1; d < NBKT; d <<= 1) {
            int u = (t >= d) ? sm[t - d] : 0;
            __syncthreads();
            sm[t] += u;
            __syncthreads();
        }
        gregion[t] = sm[t] - bv;
        if (t == NBKT - 1) gregion[NBKT] = sm[t];
        if (t == 0) cursor[0] = 0;
        if (t < 8) {  // zero sentinel rows (src == N)
            u0[(size_t)N * 8 + t] = __floats2half2_rn(0.f, 0.f);
            u1[(size_t)N * 8 + t] = __floats2half2_rn(0.f, 0.f);
        }
    }
}

// ---- bucket scatter: block-local LDS counting sort, runs at exact bases ----
// packed entry: (dst & 511) << 17 | src ; 16B paired edge loads
__global__ __launch_bounds__(256) void k_scatter(const void* __restrict__ edges,
                                                 const int* __restrict__ gregion,
                                                 const int* __restrict__ lbase,
                                                 unsigned int* __restrict__ pairs,
                                                 int E, int NBLK) {
    __shared__ unsigned int raw[C1];
    __shared__ unsigned int srt[C1];
    __shared__ unsigned short bkt[C1];
    __shared__ unsigned char sbk[C1];
    __shared__ int hist[NBKT], scn[NBKT], gb[NBKT], cur[NBKT];
    const int* e32 = (const int*)edges;
    const long long* e64 = (const long long*)edges;
    const bool is64 = detect64(e32);
    const int t = threadIdx.x;
    const int base = blockIdx.x * C1;
    const int cnt = min(C1, E - base);  // always even
    hist[t] = 0;
    cur[t] = 0;
    __syncthreads();
    for (int j = 2 * t; j < cnt; j += 512) {
        int s0, s1, d0, d1;
        if (is64) {
            longlong2 vs = *(const longlong2*)(e64 + (size_t)base + j);
            longlong2 vd = *(const longlong2*)(e64 + (size_t)E + base + j);
            s0 = (int)vs.x;
            s1 = (int)vs.y;
            d0 = (int)vd.x;
            d1 = (int)vd.y;
        } else {
            int2 vs = *(const int2*)(e32 + (size_t)base + j);
            int2 vd = *(const int2*)(e32 + (size_t)E + base + j);
            s0 = vs.x;
            s1 = vs.y;
            d0 = vd.x;
            d1 = vd.y;
        }
        int b0 = d0 >> BSH, b1 = d1 >> BSH;
        raw[j] = (unsigned int)s0 | ((unsigned int)(d0 & (NPBKT - 1)) << 17);
        raw[j + 1] = (unsigned int)s1 | ((unsigned int)(d1 & (NPBKT - 1)) << 17);
        bkt[j] = (unsigned short)b0;
        bkt[j + 1] = (unsigned short)b1;
        atomicAdd(&hist[b0], 1);
        atomicAdd(&hist[b1], 1);
    }
    __syncthreads();
    int v = hist[t];
    scn[t] = v;
    __syncthreads();
    for (int d = 1; d < NBKT; d <<= 1) {
        int u = (t >= d) ? scn[t - d] : 0;
        __syncthreads();
        scn[t] += u;
        __syncthreads();
    }
    int ex = scn[t] - v;
    gb[t] = gregion[t] + lbase[(size_t)t * NBLK + blockIdx.x];
    __syncthreads();
    scn[t] = ex;
    __syncthreads();
    for (int j = t; j < cnt; j += 256) {
        int b = bkt[j];
        int r = atomicAdd(&cur[b], 1);
        int pos = scn[b] + r;
        srt[pos] = raw[j];
        sbk[pos] = (unsigned char)b;
    }
    __syncthreads();
    for (int j = t; j < cnt; j += 256) {
        int b = sbk[j];
        pairs[gb[b] + (j - scn[b])] = srt[j];
    }
}

// ---- fused half-bucket build: count -> reserve -> stage -> burst -> prep ----
// One block per half-bucket (256 nodes). Counts degrees in LDS, reserves its
// srcs segment via one global atomicAdd, writes dinv/off2, stages self-loop +
// edges + sentinel pads in LDS, burst-writes coalesced, then computes
// u0[n] = fp16(dinv * (x[n] @ W^T)) for its nodes (2 threads/node).
__global__ __launch_bounds__(512) void k_hbuild(const unsigned int* __restrict__ pairs,
                                                const int* __restrict__ gregion,
                                                int* __restrict__ cursor,
                                                const float* __restrict__ x,
                                                const float* __restrict__ Wg,
                                                float* __restrict__ dinv,
                                                int2* __restrict__ off2,
                                                int* __restrict__ srcs,
                                                __half2* __restrict__ u0, int N) {
    const int bh = blockIdx.x;
    const int b = bh >> 1, h = bh & 1;
    const int e0 = gregion[b], e1 = gregion[b + 1];
    __shared__ int cnt[HNODES], sm[HNODES], cur[HNODES];
    __shared__ float Wl[DIMOUT * NF];
    __shared__ unsigned staged[SCAP];
    __shared__ int gb_sh;
    const int t = threadIdx.x;
    if (t < HNODES) cnt[t] = 0;
    if (t >= HNODES && t - HNODES < DIMOUT * NF) Wl[t - HNODES] = Wg[t - HNODES];
    __syncthreads();
    for (int e = e0 + t; e < e1; e += 512) {
        int dl = (int)(pairs[e] >> 17);
        if ((dl >> 8) == h) atomicAdd(&cnt[dl & (HNODES - 1)], 1);
    }
    __syncthreads();
    const int nbase = (b << BSH) + h * HNODES;
    int c = 0, p = 0;
    if (t < HNODES) {
        c = cnt[t];
        if (nbase + t < N) p = (c + 8) & ~7;  // self-loop + pad to 8
        sm[t] = p;
    }
    __syncthreads();
    for (int d = 1; d < HNODES; d <<= 1) {
        int u = (t >= d && t < HNODES) ? sm[t - d] : 0;
        __syncthreads();
        if (t < HNODES) sm[t] += u;
        __syncthreads();
    }
    const int span = sm[HNODES - 1];
    if (t == 0) gb_sh = atomicAdd(cursor, span);
    __syncthreads();
    const int gb = gb_sh;
    const bool fits = (span <= SCAP);
    if (t < HNODES) {
        int n = nbase + t;
        if (n < N) {
            int loff = sm[t] - p;
            dinv[n] = rsqrtf((float)(c + 1));
            off2[n] = make_int2(gb + loff, gb + loff + p);
            if (fits) {
                cur[t] = loff + 1;
                staged[loff] = (unsigned)n;  // self loop at slot 0
                for (int k = c + 1; k < p; ++k) staged[loff + k] = (unsigned)N;
            } else {  // fallback: direct global writes
                cur[t] = gb + loff + 1;
                srcs[gb + loff] = n;
                for (int k = c + 1; k < p; ++k) srcs[gb + loff + k] = N;
            }
        } else {
            cur[t] = 0;
        }
    }
    __syncthreads();
    if (fits) {
        for (int e = e0 + t; e < e1; e += 512) {  // L2-hot re-read
            unsigned pr = pairs[e];
            int dl = (int)(pr >> 17);
            if ((dl >> 8) == h) {
                int r = atomicAdd(&cur[dl & (HNODES - 1)], 1);  // LDS only
                staged[r] = pr & 0x1FFFFu;
            }
        }
        __syncthreads();
        for (int i = t; i < span; i += 512) srcs[gb + i] = (int)staged[i];
    } else {
        for (int e = e0 + t; e < e1; e += 512) {
            unsigned pr = pairs[e];
            int dl = (int)(pr >> 17);
            if ((dl >> 8) == h) {
                int r = atomicAdd(&cur[dl & (HNODES - 1)], 1);
                srcs[r] = (int)(pr & 0x1FFFFu);
            }
        }
    }
    // ---- prep tail: 2 threads per node, 4 half2 outputs each.
    // Reads only cnt[] (stable since count phase) + global x/W — no sync needed.
    const int l2 = t >> 1;
    const int n2 = nbase + l2;
    if (n2 < N) {
        const int qb = (t & 1) * 4;
        float dn = rsqrtf((float)(cnt[l2] + 1));
        float xr[NF];
        const float2* xr2 = (const float2*)(x + (size_t)n2 * NF);
#pragma unroll
        for (int k = 0; k < 7; ++k) {
            float2 v = xr2[k];
            xr[2 * k] = v.x;
            xr[2 * k + 1] = v.y;
        }
#pragma unroll
        for (int q = 0; q < 4; ++q) {
            const int qq = qb + q;
            float r0 = 0.f, r1 = 0.f;
#pragma unroll
            for (int f = 0; f < NF; ++f) {
                r0 += xr[f] * Wl[(2 * qq) * NF + f];
                r1 += xr[f] * Wl[(2 * qq + 1) * NF + f];
            }
            u0[(size_t)n2 * 8 + qq] = __floats2half2_rn(dn * r0, dn * r1);
        }
    }
}

// ---- hop: grid-stride, 2 nodes per wave (half-wave each), 8-way
// edge-parallel, 8B lanes, pad-8 lists. Reduce over ep = 3 shfl rounds. ----
template <int FINAL>
__global__ __launch_bounds__(256) void k_hop(const uint2* __restrict__ u8,
                                             const int* __restrict__ srcs,
                                             const int2* __restrict__ off2,
                                             const float* __restrict__ dinv,
                                             const float* __restrict__ bias,
                                             uint2* __restrict__ outh,
                                             float* __restrict__ outf, int N) {
    const int lane = threadIdx.x & 63;
    const int fp = lane & 3;          // 8B quarter of 32B row
    const int ep = (lane >> 2) & 7;   // 8 edge subgroups per half-wave
    const int half = lane >> 5;       // which node this half-wave owns
    const int wid = threadIdx.x >> 6;
    float4 breg = make_float4(0.f, 0.f, 0.f, 0.f);
    if (FINAL) breg = *(const float4*)(bias + 4 * fp);
    const int stride = gridDim.x * 8;  // 4 waves x 2 nodes per block
    for (int n0 = blockIdx.x * 8 + wid * 2; n0 < N; n0 += stride) {
        const int n = n0 + half;
        const bool act = (n < N);
        int2 oo = act ? off2[n] : make_int2(0, 0);
        float ax = 0.f, ay = 0.f, az = 0.f, aw = 0.f;
        int e = oo.x + ep;
        for (; e + 8 < oo.y; e += 16) {  // 2-deep: 16 slots per half-wave iter
            int s0 = srcs[e];
            int s1 = srcs[e + 8];
            uint2 q0 = u8[(size_t)s0 * 4 + fp];
            uint2 q1 = u8[(size_t)s1 * 4 + fp];
            float2 a0 = __half22float2(*(__half2*)&q0.x);
            float2 b0 = __half22float2(*(__half2*)&q0.y);
            float2 a1 = __half22float2(*(__half2*)&q1.x);
            float2 b1 = __half22float2(*(__half2*)&q1.y);
            ax += a0.x + a1.x;
            ay += a0.y + a1.y;
            az += b0.x + b1.x;
            aw += b0.y + b1.y;
        }
        if (e < oo.y) {  // at most one leftover 8-chunk
            int s0 = srcs[e];
            uint2 q0 = u8[(size_t)s0 * 4 + fp];
            float2 a0 = __half22float2(*(__half2*)&q0.x);
            float2 b0 = __half22float2(*(__half2*)&q0.y);
            ax += a0.x;
            ay += a0.y;
            az += b0.x;
            aw += b0.y;
        }
#pragma unroll
        for (int d = 4; d <= 16; d <<= 1) {  // reduce over ep, stays in-half
            ax += __shfl_xor(ax, d);
            ay += __shfl_xor(ay, d);
            az += __shfl_xor(az, d);
            aw += __shfl_xor(aw, d);
        }
        if (ep == 0 && act) {
            float dn = dinv[n];
            if (!FINAL) {
                float s = dn * dn;
                __half2 h0 = __floats2half2_rn(s * ax, s * ay);
                __half2 h1 = __floats2half2_rn(s * az, s * aw);
                uint2 q;
                q.x = *(unsigned*)&h0;
                q.y = *(unsigned*)&h1;
                outh[(size_t)n * 4 + fp] = q;
            } else {
                float4 o;
                o.x = dn * ax + breg.x;
                o.y = dn * ay + breg.y;
                o.z = dn * az + breg.z;
                o.w = dn * aw + breg.w;
                *(float4*)(outf + (size_t)n * DIMOUT + 4 * fp) = o;
            }
        }
    }
}

extern "C" void kernel_launch(void* const* d_in, const int* in_sizes, int n_in,
                              void* d_out, int out_size, void* d_ws, size_t ws_size,
                              hipStream_t stream) {
    const float* x = (const float*)d_in[0];
    const void* edges = d_in[1];
    const float* W = (const float*)d_in[2];
    const float* b = (const float*)d_in[3];
    float* out = (float*)d_out;

    const int N = in_sizes[0] / NF;  // 100000
    const int E = in_sizes[1] / 2;   // 3200000
    const int NBLK = (E + C1 - 1) / C1;
    const int NUSED = (N + NPBKT - 1) >> BSH;
    const int NBH = NUSED * 2;  // half-buckets

    char* ws = (char*)d_ws;
    size_t o = 0;
    auto alloc = [&](size_t bytes) -> void* {
        o = (o + 255) & ~(size_t)255;
        void* p = ws + o;
        o += bytes;
        return p;
    };
    int* cursor = (int*)alloc(16);
    int* done = (int*)alloc(16);
    int* lhistT = (int*)alloc((size_t)NBKT * NBLK * sizeof(int));
    int* lbase = (int*)alloc((size_t)NBKT * NBLK * sizeof(int));
    int* btot = (int*)alloc((size_t)NBKT * sizeof(int));
    int* gregion = (int*)alloc(((size_t)NBKT + 1) * sizeof(int));
    unsigned int* pairs = (unsigned int*)alloc((size_t)E * sizeof(unsigned int));
    int* srcs = (int*)alloc(((size_t)E + (size_t)8 * N + 256) * sizeof(int));
    int2* off2 = (int2*)alloc((size_t)N * sizeof(int2));
    float* dinv = (float*)alloc((size_t)N * sizeof(float));
    __half* u0 = (__half*)alloc((size_t)(N + 1) * 16 * sizeof(__half));
    __half* u1 = (__half*)alloc((size_t)(N + 1) * 16 * sizeof(__half));
    (void)ws_size;
    (void)n_in;
    (void)out_size;

    k_lhist<<<NBLK, 256, 0, stream>>>(edges, lhistT, done, E, NBLK);
    k_cscan<<<NBKT, 256, 0, stream>>>(lhistT, lbase, btot, gregion, cursor, done,
                                      (__half2*)u0, (__half2*)u1, NBLK, N);
    k_scatter<<<NBLK, 256, 0, stream>>>(edges, gregion, lbase, pairs, E, NBLK);
    k_hbuild<<<NBH, 512, 0, stream>>>(pairs, gregion, cursor, x, W, dinv, off2,
                                      srcs, (__half2*)u0, N);

    k_hop<0><<<2048, 256, 0, stream>>>((const uint2*)u0, srcs, off2, dinv, nullptr,
                                       (uint2*)u1, nullptr, N);
    k_hop<1><<<2048, 256, 0, stream>>>((const uint2*)u1, srcs, off2, dinv, b,
                                       nullptr, out, N);
}

// Round 21
// 112.839 us; speedup vs baseline: 1.0933x; 1.0666x over previous
//
#include <hip/hip_runtime.h>
#include <hip/hip_fp16.h>

#define NF 14
#define DIMOUT 16
#define BSH 9        // 512 nodes per bucket
#define NPBKT 512
#define NBKT 256     // bucket count (used: ceil(N/512) = 196)
#define C1 4096      // edges per block in bucket passes
#define HNODES 256   // nodes per half-bucket
#define SCAP 14336   // LDS staging capacity (entries) per half-bucket

// int64 edge buffer <=> odd 32-bit words (high halves) all zero (ids < 2^31)
__device__ __forceinline__ bool detect64(const int* e32) {
    bool is64 = true;
#pragma unroll
    for (int i = 1; i < 64; i += 2) is64 &= (e32[i] == 0);
    return is64;
}

// ---- per-block bucket histogram (transposed write); 16B paired loads ----
__global__ __launch_bounds__(256) void k_lhist(const void* __restrict__ edges,
                                               int* __restrict__ lhistT, int E, int NBLK) {
    __shared__ int h[NBKT];
    const int t = threadIdx.x;
    h[t] = 0;
    __syncthreads();
    const int* e32 = (const int*)edges;
    const long long* e64 = (const long long*)edges;
    const bool is64 = detect64(e32);
    const int base = blockIdx.x * C1;
    const int cnt = min(C1, E - base);  // always even (E, C1 even)
    if (is64) {
        const longlong2* p2 = (const longlong2*)(e64 + (size_t)E + base);
        for (int j = 2 * t; j < cnt; j += 512) {
            longlong2 v = p2[j >> 1];
            atomicAdd(&h[((int)v.x) >> BSH], 1);
            atomicAdd(&h[((int)v.y) >> BSH], 1);
        }
    } else {
        const int2* p2 = (const int2*)(e32 + (size_t)E + base);
        for (int j = 2 * t; j < cnt; j += 512) {
            int2 v = p2[j >> 1];
            atomicAdd(&h[v.x >> BSH], 1);
            atomicAdd(&h[v.y >> BSH], 1);
        }
    }
    __syncthreads();
    lhistT[(size_t)t * NBLK + blockIdx.x] = h[t];
}

// ---- per-bucket scan over blocks ----
__global__ __launch_bounds__(256) void k_cscan(const int* __restrict__ lhistT,
                                               int* __restrict__ lbase,
                                               int* __restrict__ btot, int NBLK) {
    const int b = blockIdx.x;
    const int t = threadIdx.x;
    const int IPT = (NBLK + 255) / 256;
    int v[8];
    int s = 0;
    for (int k = 0; k < IPT; ++k) {
        int j = t * IPT + k;
        int x = (j < NBLK) ? lhistT[(size_t)b * NBLK + j] : 0;
        v[k] = x;
        s += x;
    }
    __shared__ int sm[256];
    sm[t] = s;
    __syncthreads();
    for (int d = 1; d < 256; d <<= 1) {
        int u = (t >= d) ? sm[t - d] : 0;
        __syncthreads();
        sm[t] += u;
        __syncthreads();
    }
    int run = sm[t] - s;
    for (int k = 0; k < IPT; ++k) {
        int j = t * IPT + k;
        if (j < NBLK) {
            lbase[(size_t)b * NBLK + j] = run;
            run += v[k];
        }
    }
    if (t == 255) btot[b] = sm[255];
}

// ---- scan bucket totals -> regions; zero hbuild cursor + sentinel rows ----
__global__ __launch_bounds__(NBKT) void k_gscan(const int* __restrict__ btot,
                                                int* __restrict__ gregion,
                                                int* __restrict__ cursor,
                                                __half2* __restrict__ u0,
                                                __half2* __restrict__ u1, int N) {
    __shared__ int sm[NBKT];
    int t = threadIdx.x;
    int v = btot[t];
    sm[t] = v;
    __syncthreads();
    for (int d = 1; d < NBKT; d <<= 1) {
        int u = (t >= d) ? sm[t - d] : 0;
        __syncthreads();
        sm[t] += u;
        __syncthreads();
    }
    gregion[t] = sm[t] - v;
    if (t == NBKT - 1) gregion[NBKT] = sm[t];
    if (t == 0) cursor[0] = 0;
    if (t < 8) {  // zero sentinel rows (src == N)
        u0[(size_t)N * 8 + t] = __floats2half2_rn(0.f, 0.f);
        u1[(size_t)N * 8 + t] = __floats2half2_rn(0.f, 0.f);
    }
}

// ---- bucket scatter: block-local LDS counting sort, runs at exact bases ----
// packed entry: (dst & 511) << 17 | src ; 16B paired edge loads
__global__ __launch_bounds__(256) void k_scatter(const void* __restrict__ edges,
                                                 const int* __restrict__ gregion,
                                                 const int* __restrict__ lbase,
                                                 unsigned int* __restrict__ pairs,
                                                 int E, int NBLK) {
    __shared__ unsigned int raw[C1];
    __shared__ unsigned int srt[C1];
    __shared__ unsigned short bkt[C1];
    __shared__ unsigned char sbk[C1];
    __shared__ int hist[NBKT], scn[NBKT], gb[NBKT], cur[NBKT];
    const int* e32 = (const int*)edges;
    const long long* e64 = (const long long*)edges;
    const bool is64 = detect64(e32);
    const int t = threadIdx.x;
    const int base = blockIdx.x * C1;
    const int cnt = min(C1, E - base);  // always even
    hist[t] = 0;
    cur[t] = 0;
    __syncthreads();
    for (int j = 2 * t; j < cnt; j += 512) {
        int s0, s1, d0, d1;
        if (is64) {
            longlong2 vs = *(const longlong2*)(e64 + (size_t)base + j);
            longlong2 vd = *(const longlong2*)(e64 + (size_t)E + base + j);
            s0 = (int)vs.x;
            s1 = (int)vs.y;
            d0 = (int)vd.x;
            d1 = (int)vd.y;
        } else {
            int2 vs = *(const int2*)(e32 + (size_t)base + j);
            int2 vd = *(const int2*)(e32 + (size_t)E + base + j);
            s0 = vs.x;
            s1 = vs.y;
            d0 = vd.x;
            d1 = vd.y;
        }
        int b0 = d0 >> BSH, b1 = d1 >> BSH;
        raw[j] = (unsigned int)s0 | ((unsigned int)(d0 & (NPBKT - 1)) << 17);
        raw[j + 1] = (unsigned int)s1 | ((unsigned int)(d1 & (NPBKT - 1)) << 17);
        bkt[j] = (unsigned short)b0;
        bkt[j + 1] = (unsigned short)b1;
        atomicAdd(&hist[b0], 1);
        atomicAdd(&hist[b1], 1);
    }
    __syncthreads();
    int v = hist[t];
    scn[t] = v;
    __syncthreads();
    for (int d = 1; d < NBKT; d <<= 1) {
        int u = (t >= d) ? scn[t - d] : 0;
        __syncthreads();
        scn[t] += u;
        __syncthreads();
    }
    int ex = scn[t] - v;
    gb[t] = gregion[t] + lbase[(size_t)t * NBLK + blockIdx.x];
    __syncthreads();
    scn[t] = ex;
    __syncthreads();
    for (int j = t; j < cnt; j += 256) {
        int b = bkt[j];
        int r = atomicAdd(&cur[b], 1);
        int pos = scn[b] + r;
        srt[pos] = raw[j];
        sbk[pos] = (unsigned char)b;
    }
    __syncthreads();
    for (int j = t; j < cnt; j += 256) {
        int b = sbk[j];
        pairs[gb[b] + (j - scn[b])] = srt[j];
    }
}

// ---- fused half-bucket build: count -> reserve -> stage -> burst -> prep ----
// One block per half-bucket (256 nodes). Counts degrees in LDS, reserves its
// srcs segment via one global atomicAdd, writes dinv/off2, stages self-loop +
// edges + sentinel pads in LDS, burst-writes coalesced, then computes
// u0[n] = fp16(dinv * (x[n] @ W^T)) for its nodes (2 threads/node).
__global__ __launch_bounds__(512) void k_hbuild(const unsigned int* __restrict__ pairs,
                                                const int* __restrict__ gregion,
                                                int* __restrict__ cursor,
                                                const float* __restrict__ x,
                                                const float* __restrict__ Wg,
                                                float* __restrict__ dinv,
                                                int2* __restrict__ off2,
                                                int* __restrict__ srcs,
                                                __half2* __restrict__ u0, int N) {
    const int bh = blockIdx.x;
    const int b = bh >> 1, h = bh & 1;
    const int e0 = gregion[b], e1 = gregion[b + 1];
    __shared__ int cnt[HNODES], sm[HNODES], cur[HNODES];
    __shared__ float Wl[DIMOUT * NF];
    __shared__ unsigned staged[SCAP];
    __shared__ int gb_sh;
    const int t = threadIdx.x;
    if (t < HNODES) cnt[t] = 0;
    if (t >= HNODES && t - HNODES < DIMOUT * NF) Wl[t - HNODES] = Wg[t - HNODES];
    __syncthreads();
    for (int e = e0 + t; e < e1; e += 512) {
        int dl = (int)(pairs[e] >> 17);
        if ((dl >> 8) == h) atomicAdd(&cnt[dl & (HNODES - 1)], 1);
    }
    __syncthreads();
    const int nbase = (b << BSH) + h * HNODES;
    int c = 0, p = 0;
    if (t < HNODES) {
        c = cnt[t];
        if (nbase + t < N) p = (c + 8) & ~7;  // self-loop + pad to 8
        sm[t] = p;
    }
    __syncthreads();
    for (int d = 1; d < HNODES; d <<= 1) {
        int u = (t >= d && t < HNODES) ? sm[t - d] : 0;
        __syncthreads();
        if (t < HNODES) sm[t] += u;
        __syncthreads();
    }
    const int span = sm[HNODES - 1];
    if (t == 0) gb_sh = atomicAdd(cursor, span);
    __syncthreads();
    const int gb = gb_sh;
    const bool fits = (span <= SCAP);
    if (t < HNODES) {
        int n = nbase + t;
        if (n < N) {
            int loff = sm[t] - p;
            dinv[n] = rsqrtf((float)(c + 1));
            off2[n] = make_int2(gb + loff, gb + loff + p);
            if (fits) {
                cur[t] = loff + 1;
                staged[loff] = (unsigned)n;  // self loop at slot 0
                for (int k = c + 1; k < p; ++k) staged[loff + k] = (unsigned)N;
            } else {  // fallback: direct global writes
                cur[t] = gb + loff + 1;
                srcs[gb + loff] = n;
                for (int k = c + 1; k < p; ++k) srcs[gb + loff + k] = N;
            }
        } else {
            cur[t] = 0;
        }
    }
    __syncthreads();
    if (fits) {
        for (int e = e0 + t; e < e1; e += 512) {  // L2-hot re-read
            unsigned pr = pairs[e];
            int dl = (int)(pr >> 17);
            if ((dl >> 8) == h) {
                int r = atomicAdd(&cur[dl & (HNODES - 1)], 1);  // LDS only
                staged[r] = pr & 0x1FFFFu;
            }
        }
        __syncthreads();
        for (int i = t; i < span; i += 512) srcs[gb + i] = (int)staged[i];
    } else {
        for (int e = e0 + t; e < e1; e += 512) {
            unsigned pr = pairs[e];
            int dl = (int)(pr >> 17);
            if ((dl >> 8) == h) {
                int r = atomicAdd(&cur[dl & (HNODES - 1)], 1);
                srcs[r] = (int)(pr & 0x1FFFFu);
            }
        }
    }
    // ---- prep tail: 2 threads per node, 4 half2 outputs each.
    // Reads only cnt[] (stable since count phase) + global x/W — no sync needed.
    const int l2 = t >> 1;
    const int n2 = nbase + l2;
    if (n2 < N) {
        const int qb = (t & 1) * 4;
        float dn = rsqrtf((float)(cnt[l2] + 1));
        float xr[NF];
        const float2* xr2 = (const float2*)(x + (size_t)n2 * NF);
#pragma unroll
        for (int k = 0; k < 7; ++k) {
            float2 v = xr2[k];
            xr[2 * k] = v.x;
            xr[2 * k + 1] = v.y;
        }
#pragma unroll
        for (int q = 0; q < 4; ++q) {
            const int qq = qb + q;
            float r0 = 0.f, r1 = 0.f;
#pragma unroll
            for (int f = 0; f < NF; ++f) {
                r0 += xr[f] * Wl[(2 * qq) * NF + f];
                r1 += xr[f] * Wl[(2 * qq + 1) * NF + f];
            }
            u0[(size_t)n2 * 8 + qq] = __floats2half2_rn(dn * r0, dn * r1);
        }
    }
}

// ---- hop: grid-stride, 2 nodes per wave (half-wave each), 8-way
// edge-parallel, 8B lanes, pad-8 lists. Reduce over ep = 3 shfl rounds. ----
template <int FINAL>
__global__ __launch_bounds__(256) void k_hop(const uint2* __restrict__ u8,
                                             const int* __restrict__ srcs,
                                             const int2* __restrict__ off2,
                                             const float* __restrict__ dinv,
                                             const float* __restrict__ bias,
                                             uint2* __restrict__ outh,
                                             float* __restrict__ outf, int N) {
    const int lane = threadIdx.x & 63;
    const int fp = lane & 3;          // 8B quarter of 32B row
    const int ep = (lane >> 2) & 7;   // 8 edge subgroups per half-wave
    const int half = lane >> 5;       // which node this half-wave owns
    const int wid = threadIdx.x >> 6;
    float4 breg = make_float4(0.f, 0.f, 0.f, 0.f);
    if (FINAL) breg = *(const float4*)(bias + 4 * fp);
    const int stride = gridDim.x * 8;  // 4 waves x 2 nodes per block
    for (int n0 = blockIdx.x * 8 + wid * 2; n0 < N; n0 += stride) {
        const int n = n0 + half;
        const bool act = (n < N);
        int2 oo = act ? off2[n] : make_int2(0, 0);
        float ax = 0.f, ay = 0.f, az = 0.f, aw = 0.f;
        int e = oo.x + ep;
        for (; e + 8 < oo.y; e += 16) {  // 2-deep: 16 slots per half-wave iter
            int s0 = srcs[e];
            int s1 = srcs[e + 8];
            uint2 q0 = u8[(size_t)s0 * 4 + fp];
            uint2 q1 = u8[(size_t)s1 * 4 + fp];
            float2 a0 = __half22float2(*(__half2*)&q0.x);
            float2 b0 = __half22float2(*(__half2*)&q0.y);
            float2 a1 = __half22float2(*(__half2*)&q1.x);
            float2 b1 = __half22float2(*(__half2*)&q1.y);
            ax += a0.x + a1.x;
            ay += a0.y + a1.y;
            az += b0.x + b1.x;
            aw += b0.y + b1.y;
        }
        if (e < oo.y) {  // at most one leftover 8-chunk
            int s0 = srcs[e];
            uint2 q0 = u8[(size_t)s0 * 4 + fp];
            float2 a0 = __half22float2(*(__half2*)&q0.x);
            float2 b0 = __half22float2(*(__half2*)&q0.y);
            ax += a0.x;
            ay += a0.y;
            az += b0.x;
            aw += b0.y;
        }
#pragma unroll
        for (int d = 4; d <= 16; d <<= 1) {  // reduce over ep, stays in-half
            ax += __shfl_xor(ax, d);
            ay += __shfl_xor(ay, d);
            az += __shfl_xor(az, d);
            aw += __shfl_xor(aw, d);
        }
        if (ep == 0 && act) {
            float dn = dinv[n];
            if (!FINAL) {
                float s = dn * dn;
                __half2 h0 = __floats2half2_rn(s * ax, s * ay);
                __half2 h1 = __floats2half2_rn(s * az, s * aw);
                uint2 q;
                q.x = *(unsigned*)&h0;
                q.y = *(unsigned*)&h1;
                outh[(size_t)n * 4 + fp] = q;
            } else {
                float4 o;
                o.x = dn * ax + breg.x;
                o.y = dn * ay + breg.y;
                o.z = dn * az + breg.z;
                o.w = dn * aw + breg.w;
                *(float4*)(outf + (size_t)n * DIMOUT + 4 * fp) = o;
            }
        }
    }
}

extern "C" void kernel_launch(void* const* d_in, const int* in_sizes, int n_in,
                              void* d_out, int out_size, void* d_ws, size_t ws_size,
                              hipStream_t stream) {
    const float* x = (const float*)d_in[0];
    const void* edges = d_in[1];
    const float* W = (const float*)d_in[2];
    const float* b = (const float*)d_in[3];
    float* out = (float*)d_out;

    const int N = in_sizes[0] / NF;  // 100000
    const int E = in_sizes[1] / 2;   // 3200000
    const int NBLK = (E + C1 - 1) / C1;
    const int NUSED = (N + NPBKT - 1) >> BSH;
    const int NBH = NUSED * 2;  // half-buckets

    char* ws = (char*)d_ws;
    size_t o = 0;
    auto alloc = [&](size_t bytes) -> void* {
        o = (o + 255) & ~(size_t)255;
        void* p = ws + o;
        o += bytes;
        return p;
    };
    int* cursor = (int*)alloc(16);
    int* lhistT = (int*)alloc((size_t)NBKT * NBLK * sizeof(int));
    int* lbase = (int*)alloc((size_t)NBKT * NBLK * sizeof(int));
    int* btot = (int*)alloc((size_t)NBKT * sizeof(int));
    int* gregion = (int*)alloc(((size_t)NBKT + 1) * sizeof(int));
    unsigned int* pairs = (unsigned int*)alloc((size_t)E * sizeof(unsigned int));
    int* srcs = (int*)alloc(((size_t)E + (size_t)8 * N + 256) * sizeof(int));
    int2* off2 = (int2*)alloc((size_t)N * sizeof(int2));
    float* dinv = (float*)alloc((size_t)N * sizeof(float));
    __half* u0 = (__half*)alloc((size_t)(N + 1) * 16 * sizeof(__half));
    __half* u1 = (__half*)alloc((size_t)(N + 1) * 16 * sizeof(__half));
    (void)ws_size;
    (void)n_in;
    (void)out_size;

    k_lhist<<<NBLK, 256, 0, stream>>>(edges, lhistT, E, NBLK);
    k_cscan<<<NBKT, 256, 0, stream>>>(lhistT, lbase, btot, NBLK);
    k_gscan<<<1, NBKT, 0, stream>>>(btot, gregion, cursor, (__half2*)u0,
                                    (__half2*)u1, N);
    k_scatter<<<NBLK, 256, 0, stream>>>(edges, gregion, lbase, pairs, E, NBLK);
    k_hbuild<<<NBH, 512, 0, stream>>>(pairs, gregion, cursor, x, W, dinv, off2,
                                      srcs, (__half2*)u0, N);

    k_hop<0><<<2048, 256, 0, stream>>>((const uint2*)u0, srcs, off2, dinv, nullptr,
                                       (uint2*)u1, nullptr, N);
    k_hop<1><<<2048, 256, 0, stream>>>((const uint2*)u1, srcs, off2, dinv, b,
                                       nullptr, out, N);
}